// Round 10
// baseline (95.766 us; speedup 1.0000x reference)
//
#include <hip/hip_runtime.h>

#define B_ 4
#define C_ 64
#define H_ 96
#define W_ 96
#define KS_ 7
#define NPIX (H_ * W_)   // 9216
#define LDK 108          // K LDS row stride (floats)
#define LDV 112          // V LDS row stride (ushorts) -> 224B rows, 16B-aligned

typedef __attribute__((ext_vector_type(8))) short short8;
typedef __attribute__((ext_vector_type(8))) unsigned short ushort8;
typedef __attribute__((ext_vector_type(4))) float f32x4;

static __device__ inline ushort f2bf(float f) {
    union { float f; unsigned u; } v; v.f = f;
    unsigned r = (v.u + 0x7fff + ((v.u >> 16) & 1)) >> 16;   // RNE
    return (ushort)r;
}
static __device__ inline float bf2f(ushort u) {
    union { unsigned u; float f; } v; v.u = ((unsigned)u) << 16; return v.f;
}

// ws layout: qkv float[B][192][9216] (q rows 0-63, k 64-127, v 128-191), then rel float[64]

// ---- MFMA conv: 32-pix x 192-oc per block; A-frags cvt'd from global in regs ----
__global__ __launch_bounds__(256) void mfma_conv_kernel(
    const float* __restrict__ in,
    const float* __restrict__ qw, const float* __restrict__ qb,
    const float* __restrict__ kw, const float* __restrict__ kb,
    const float* __restrict__ vw, const float* __restrict__ vb,
    const float* __restrict__ relh, const float* __restrict__ relw,
    float* __restrict__ qkv, float* __restrict__ rel_out)
{
    const int b    = blockIdx.y;
    const int pix0 = blockIdx.x * 32;
    const int t    = threadIdx.x;
    const int lane = t & 63;
    const int wv   = t >> 6;

    if (blockIdx.x == 0 && b == 0 && t < 49) {   // rel precompute (one block)
        const int i = t / KS_, j = t % KS_;
        float s = 0.f;
        #pragma unroll
        for (int cc = 0; cc < C_ / 2; ++cc)
            s += relh[cc * KS_ + i] + relw[cc * KS_ + j];
        rel_out[t] = s;
    }

    __shared__ ushort xs[32 * 64];   // [pix][ch] bf16, byte ^= (pix&7)<<4

    {   // stage X tile (32 pix x 64 ch)
        const int pix = t & 31, cg = t >> 5;
        const float* xp = in + (size_t)b * C_ * NPIX + pix0 + pix;
        #pragma unroll
        for (int g = 0; g < 2; ++g) {
            const int ch = (cg + 8 * g) * 4;
            float x0 = xp[(size_t)(ch    ) * NPIX];
            float x1 = xp[(size_t)(ch + 1) * NPIX];
            float x2 = xp[(size_t)(ch + 2) * NPIX];
            float x3 = xp[(size_t)(ch + 3) * NPIX];
            ushort4 u = make_ushort4(f2bf(x0), f2bf(x1), f2bf(x2), f2bf(x3));
            unsigned byte = (unsigned)(pix * 128 + ch * 2) ^ (unsigned)((pix & 7) << 4);
            *reinterpret_cast<ushort4*>(reinterpret_cast<char*>(xs) + byte) = u;
        }
    }

    // A fragments + bias straight from global (overlaps X staging; no barrier dep)
    short8 afr[3][2];
    float  bi[3][4];
    #pragma unroll
    for (int i = 0; i < 3; ++i) {
        const int mt  = 3 * wv + i;                 // wave-uniform
        const int row = mt * 16 + (lane & 15);
        const float* wsrc = (mt < 4) ? qw + row * 64
                          : (mt < 8) ? kw + (row - 64) * 64
                                     : vw + (row - 128) * 64;
        #pragma unroll
        for (int ka = 0; ka < 2; ++ka) {
            const int kk = ka * 32 + (lane >> 4) * 8;
            float4 a = *reinterpret_cast<const float4*>(wsrc + kk);
            float4 c = *reinterpret_cast<const float4*>(wsrc + kk + 4);
            short8 s;
            s[0] = (short)f2bf(a.x); s[1] = (short)f2bf(a.y);
            s[2] = (short)f2bf(a.z); s[3] = (short)f2bf(a.w);
            s[4] = (short)f2bf(c.x); s[5] = (short)f2bf(c.y);
            s[6] = (short)f2bf(c.z); s[7] = (short)f2bf(c.w);
            afr[i][ka] = s;
        }
        const int brow = mt * 16 + (lane >> 4) * 4;
        const float* bsrc = (mt < 4) ? qb + brow
                          : (mt < 8) ? kb + (brow - 64)
                                     : vb + (brow - 128);
        #pragma unroll
        for (int r = 0; r < 4; ++r) bi[i][r] = bsrc[r];
    }
    __syncthreads();

    short8 bfr[2][2];
    #pragma unroll
    for (int nt = 0; nt < 2; ++nt) {
        const int pl = nt * 16 + (lane & 15);
        #pragma unroll
        for (int ka = 0; ka < 2; ++ka) {
            const int kk = ka * 32 + (lane >> 4) * 8;
            unsigned byte = (unsigned)(pl * 128 + kk * 2) ^ (unsigned)((pl & 7) << 4);
            bfr[nt][ka] = *reinterpret_cast<const short8*>(
                reinterpret_cast<const char*>(xs) + byte);
        }
    }
    f32x4 acc[3][2];
    #pragma unroll
    for (int i = 0; i < 3; ++i) {
        f32x4 bv;
        #pragma unroll
        for (int r = 0; r < 4; ++r) bv[r] = bi[i][r];
        #pragma unroll
        for (int nt = 0; nt < 2; ++nt) acc[i][nt] = bv;
    }
    #pragma unroll
    for (int i = 0; i < 3; ++i) {
        #pragma unroll
        for (int nt = 0; nt < 2; ++nt) {
            acc[i][nt] = __builtin_amdgcn_mfma_f32_16x16x32_bf16(
                afr[i][0], bfr[nt][0], acc[i][nt], 0, 0, 0);
            acc[i][nt] = __builtin_amdgcn_mfma_f32_16x16x32_bf16(
                afr[i][1], bfr[nt][1], acc[i][nt], 0, 0, 0);
        }
    }
    #pragma unroll
    for (int i = 0; i < 3; ++i) {
        #pragma unroll
        for (int r = 0; r < 4; ++r) {
            const int row = (3 * wv + i) * 16 + (lane >> 4) * 4 + r;
            float* op = qkv + ((size_t)b * 192 + row) * NPIX + pix0 + (lane & 15);
            #pragma unroll
            for (int nt = 0; nt < 2; ++nt)
                op[nt * 16] = acc[i][nt][r];
        }
    }
}

// ---- attention: K fp32 LDS, V bf16 LDS, rel via scalar loads, exp2 domain ----
__global__ __launch_bounds__(384) void attn_kernel(
    const float* __restrict__ qkv,
    const float* __restrict__ kb, const float* __restrict__ vb,
    const float* __restrict__ rel, float* __restrict__ out)
{
    const int bx   = blockIdx.x;
    const int tile = bx % 3;
    const int c    = (bx / 3) % C_;
    const int b    = bx / (3 * C_);
    const int ho0  = tile * 32;
    const int t    = threadIdx.x;

    __shared__ float  ksl[38 * LDK];    // 16416 B
    __shared__ ushort vsl[38 * LDV];    //  8512 B

    const float kbias = kb[c];
    const float vbias = vb[c];
    const float* kg = qkv + ((size_t)b * 192 +  64 + c) * NPIX;
    const float* vg = qkv + ((size_t)b * 192 + 128 + c) * NPIX;

    // stage: 38 rows x 26 float4-slots = 988 slots each for K and V
    #pragma unroll
    for (int s0 = 0; s0 < 3; ++s0) {
        const int slot = t + s0 * 384;
        if (slot < 38 * 26) {
            const int rl = slot / 26, c4 = (slot - rl * 26) * 4;
            const int gr = ho0 + rl - 3;
            const bool rin = (gr >= 0 && gr < H_);
            const int grc = rin ? gr : 0;
            float kv[4], vv[4];
            #pragma unroll
            for (int e = 0; e < 4; ++e) {
                const int gc  = c4 + e - 3;
                const bool inb = rin && (gc >= 0) && (gc < W_);
                const int gcc = gc < 0 ? 0 : (gc > 95 ? 95 : gc);
                const int gi  = grc * W_ + gcc;
                const float kl = kg[gi], vl = vg[gi];
                kv[e] = inb ? kl : kbias;
                vv[e] = inb ? vl : vbias;
            }
            *reinterpret_cast<float4*>(&ksl[rl * LDK + c4]) =
                make_float4(kv[0], kv[1], kv[2], kv[3]);
            *reinterpret_cast<ushort4*>(&vsl[rl * LDV + c4]) =
                make_ushort4(f2bf(vv[0]), f2bf(vv[1]), f2bf(vv[2]), f2bf(vv[3]));
        }
    }
    __syncthreads();

    const int r0   = t / 12;
    const int rest = t % 12;
    const int w0   = (rest >> 1) * 16;
    const int half = rest & 1;
    const int ho   = ho0 + r0;

    const float LOG2E = 1.44269504f;
    const float* qp = qkv + ((size_t)b * 192 + c) * NPIX + ho * W_ + w0;
    float qs[16];
    #pragma unroll
    for (int tt = 0; tt < 16; tt += 4) {
        float4 f = *reinterpret_cast<const float4*>(qp + tt);
        qs[tt] = f.x * LOG2E; qs[tt + 1] = f.y * LOG2E;
        qs[tt + 2] = f.z * LOG2E; qs[tt + 3] = f.w * LOG2E;
    }
    float qsum = 0.f;
    #pragma unroll
    for (int tt = 0; tt < 16; ++tt) qsum += qs[tt];

    float p[49];
    #pragma unroll
    for (int i = 0; i < KS_; ++i) {
        float kr[22];
        const float* kp = &ksl[(r0 + i) * LDK + w0];
        #pragma unroll
        for (int tt = 0; tt < 20; tt += 4) {
            float4 f = *reinterpret_cast<const float4*>(kp + tt);
            kr[tt] = f.x; kr[tt + 1] = f.y; kr[tt + 2] = f.z; kr[tt + 3] = f.w;
        }
        float2 f2 = *reinterpret_cast<const float2*>(kp + 20);
        kr[20] = f2.x; kr[21] = f2.y;
        #pragma unroll
        for (int j = 0; j < KS_; ++j) {
            float s0 = 0.f, s1 = 0.f, s2 = 0.f, s3 = 0.f;
            #pragma unroll
            for (int tt = 0; tt < 16; tt += 4) {
                s0 = fmaf(qs[tt],     kr[tt + j],     s0);
                s1 = fmaf(qs[tt + 1], kr[tt + 1 + j], s1);
                s2 = fmaf(qs[tt + 2], kr[tt + 2 + j], s2);
                s3 = fmaf(qs[tt + 3], kr[tt + 3 + j], s3);
            }
            // rel[] has uniform address + compile-time index -> scalar loads
            p[i * KS_ + j] = (s0 + s1) + (s2 + s3) + qsum * rel[i * KS_ + j];
        }
    }

    // softmax in log2 domain
    float m0 = p[0], m1 = p[1], m2 = p[2], m3 = p[3];
    #pragma unroll
    for (int kk = 4; kk < 48; kk += 4) {
        m0 = fmaxf(m0, p[kk]);     m1 = fmaxf(m1, p[kk + 1]);
        m2 = fmaxf(m2, p[kk + 2]); m3 = fmaxf(m3, p[kk + 3]);
    }
    float m = fmaxf(fmaxf(fmaxf(m0, m1), fmaxf(m2, m3)), p[48]);

    float e0 = 0.f, e1 = 0.f, e2 = 0.f, e3 = 0.f;
    #pragma unroll
    for (int kk = 0; kk < 48; kk += 4) {
        float a0 = exp2f(p[kk]     - m);
        float a1 = exp2f(p[kk + 1] - m);
        float a2 = exp2f(p[kk + 2] - m);
        float a3 = exp2f(p[kk + 3] - m);
        p[kk] = a0; p[kk + 1] = a1; p[kk + 2] = a2; p[kk + 3] = a3;
        e0 += a0; e1 += a1; e2 += a2; e3 += a3;
    }
    float a48 = exp2f(p[48] - m);
    p[48] = a48;
    const float inv = 1.f / ((e0 + e1) + (e2 + e3) + a48);

    // PV for d = half*8 .. half*8+7 (V from bf16 LDS)
    float o8[8];
    #pragma unroll
    for (int d = 0; d < 8; ++d) o8[d] = 0.f;

    #pragma unroll
    for (int i = 0; i < KS_; ++i) {
        const ushort* vp = &vsl[(r0 + i) * LDV + w0 + half * 8];
        ushort8 u0 = *reinterpret_cast<const ushort8*>(vp);
        ushort8 u1 = *reinterpret_cast<const ushort8*>(vp + 8);
        float vf[14];
        #pragma unroll
        for (int e = 0; e < 8; ++e) vf[e] = bf2f(u0[e]);
        #pragma unroll
        for (int e = 0; e < 6; ++e) vf[8 + e] = bf2f(u1[e]);
        #pragma unroll
        for (int j = 0; j < KS_; ++j) {
            float wgt = p[i * KS_ + j];
            #pragma unroll
            for (int d = 0; d < 8; ++d) o8[d] = fmaf(wgt, vf[d + j], o8[d]);
        }
    }

    float* op = out + (((size_t)b * C_ + c) * H_ + ho) * W_ + w0 + half * 8;
    #pragma unroll
    for (int d = 0; d < 8; d += 4) {
        float4 f;
        f.x = fmaxf(o8[d]     * inv, 0.f);
        f.y = fmaxf(o8[d + 1] * inv, 0.f);
        f.z = fmaxf(o8[d + 2] * inv, 0.f);
        f.w = fmaxf(o8[d + 3] * inv, 0.f);
        *reinterpret_cast<float4*>(op + d) = f;
    }
}

extern "C" void kernel_launch(void* const* d_in, const int* in_sizes, int n_in,
                              void* d_out, int out_size, void* d_ws, size_t ws_size,
                              hipStream_t stream) {
    const float* in   = (const float*)d_in[0];
    const float* qw   = (const float*)d_in[1];
    const float* qb   = (const float*)d_in[2];
    const float* kw   = (const float*)d_in[3];
    const float* kb   = (const float*)d_in[4];
    const float* vw   = (const float*)d_in[5];
    const float* vb   = (const float*)d_in[6];
    const float* relh = (const float*)d_in[7];
    const float* relw = (const float*)d_in[8];
    float* out = (float*)d_out;

    float* qkv = (float*)d_ws;                       // [B][192][9216]
    float* rel = qkv + (size_t)B_ * 192 * NPIX;      // [64]

    // MEASUREMENT ROUND: conv launched 5x (idempotent — same inputs -> same qkv).
    // R9: conv + attn = 42.7 us.  Here: D = 5*conv + attn
    //   => conv = (D - 42.7)/4,  attn = 42.7 - conv.
    dim3 cgrid(NPIX / 32, B_);   // 288 x 4 = 1152 blocks
    mfma_conv_kernel<<<cgrid, 256, 0, stream>>>(in, qw, qb, kw, kb, vw, vb,
                                                relh, relw, qkv, rel);
    mfma_conv_kernel<<<cgrid, 256, 0, stream>>>(in, qw, qb, kw, kb, vw, vb,
                                                relh, relw, qkv, rel);
    mfma_conv_kernel<<<cgrid, 256, 0, stream>>>(in, qw, qb, kw, kb, vw, vb,
                                                relh, relw, qkv, rel);
    mfma_conv_kernel<<<cgrid, 256, 0, stream>>>(in, qw, qb, kw, kb, vw, vb,
                                                relh, relw, qkv, rel);
    mfma_conv_kernel<<<cgrid, 256, 0, stream>>>(in, qw, qb, kw, kb, vw, vb,
                                                relh, relw, qkv, rel);

    dim3 agrid(B_ * C_ * 3);     // 768 blocks x 384 threads
    attn_kernel<<<agrid, 384, 0, stream>>>(qkv, kb, vb, rel, out);
}

// Round 11
// 54.274 us; speedup vs baseline: 1.7645x; 1.7645x over previous
//
#include <hip/hip_runtime.h>

#define B_ 4
#define C_ 64
#define H_ 96
#define W_ 96
#define KS_ 7
#define NPIX (H_ * W_)   // 9216
#define LDK 108          // K LDS row stride (floats)
#define LDV 112          // V LDS row stride (ushorts)

typedef __attribute__((ext_vector_type(8))) short short8;
typedef __attribute__((ext_vector_type(8))) unsigned short ushort8;
typedef __attribute__((ext_vector_type(4))) float f32x4;

static __device__ inline ushort f2bf(float f) {
    union { float f; unsigned u; } v; v.f = f;
    unsigned r = (v.u + 0x7fff + ((v.u >> 16) & 1)) >> 16;   // RNE
    return (ushort)r;
}
static __device__ inline float bf2f(ushort u) {
    union { unsigned u; float f; } v; v.u = ((unsigned)u) << 16; return v.f;
}

// ws layout: qf float[B][64][9216] ; kvb ushort[B][128][9216] (k rows 0-63, v 64-127) ; rel float[64]

__global__ __launch_bounds__(256) void mfma_conv_kernel(
    const float* __restrict__ in,
    const float* __restrict__ qw, const float* __restrict__ qb,
    const float* __restrict__ kw, const float* __restrict__ kb,
    const float* __restrict__ vw, const float* __restrict__ vb,
    const float* __restrict__ relh, const float* __restrict__ relw,
    float* __restrict__ qf, ushort* __restrict__ kvb, float* __restrict__ rel_out)
{
    const int b    = blockIdx.y;
    const int pix0 = blockIdx.x * 32;
    const int t    = threadIdx.x;
    const int lane = t & 63;
    const int wv   = t >> 6;

    if (blockIdx.x == 0 && b == 0 && t < 49) {   // rel precompute (one block)
        const int i = t / KS_, j = t % KS_;
        float s = 0.f;
        #pragma unroll
        for (int cc = 0; cc < C_ / 2; ++cc)
            s += relh[cc * KS_ + i] + relw[cc * KS_ + j];
        rel_out[t] = s;
    }

    __shared__ ushort xs[32 * 64];   // [pix][ch] bf16, byte ^= (pix&7)<<4

    {   // stage X tile (32 pix x 64 ch)
        const int pix = t & 31, cg = t >> 5;
        const float* xp = in + (size_t)b * C_ * NPIX + pix0 + pix;
        #pragma unroll
        for (int g = 0; g < 2; ++g) {
            const int ch = (cg + 8 * g) * 4;
            float x0 = xp[(size_t)(ch    ) * NPIX];
            float x1 = xp[(size_t)(ch + 1) * NPIX];
            float x2 = xp[(size_t)(ch + 2) * NPIX];
            float x3 = xp[(size_t)(ch + 3) * NPIX];
            ushort4 u = make_ushort4(f2bf(x0), f2bf(x1), f2bf(x2), f2bf(x3));
            unsigned byte = (unsigned)(pix * 128 + ch * 2) ^ (unsigned)((pix & 7) << 4);
            *reinterpret_cast<ushort4*>(reinterpret_cast<char*>(xs) + byte) = u;
        }
    }

    // A fragments + bias straight from global
    short8 afr[3][2];
    float  bi[3][4];
    #pragma unroll
    for (int i = 0; i < 3; ++i) {
        const int mt  = 3 * wv + i;
        const int row = mt * 16 + (lane & 15);
        const float* wsrc = (mt < 4) ? qw + row * 64
                          : (mt < 8) ? kw + (row - 64) * 64
                                     : vw + (row - 128) * 64;
        #pragma unroll
        for (int ka = 0; ka < 2; ++ka) {
            const int kk = ka * 32 + (lane >> 4) * 8;
            float4 a = *reinterpret_cast<const float4*>(wsrc + kk);
            float4 c = *reinterpret_cast<const float4*>(wsrc + kk + 4);
            short8 s;
            s[0] = (short)f2bf(a.x); s[1] = (short)f2bf(a.y);
            s[2] = (short)f2bf(a.z); s[3] = (short)f2bf(a.w);
            s[4] = (short)f2bf(c.x); s[5] = (short)f2bf(c.y);
            s[6] = (short)f2bf(c.z); s[7] = (short)f2bf(c.w);
            afr[i][ka] = s;
        }
        const int brow = mt * 16 + (lane >> 4) * 4;
        const float* bsrc = (mt < 4) ? qb + brow
                          : (mt < 8) ? kb + (brow - 64)
                                     : vb + (brow - 128);
        #pragma unroll
        for (int r = 0; r < 4; ++r) bi[i][r] = bsrc[r];
    }
    __syncthreads();

    short8 bfr[2][2];
    #pragma unroll
    for (int nt = 0; nt < 2; ++nt) {
        const int pl = nt * 16 + (lane & 15);
        #pragma unroll
        for (int ka = 0; ka < 2; ++ka) {
            const int kk = ka * 32 + (lane >> 4) * 8;
            unsigned byte = (unsigned)(pl * 128 + kk * 2) ^ (unsigned)((pl & 7) << 4);
            bfr[nt][ka] = *reinterpret_cast<const short8*>(
                reinterpret_cast<const char*>(xs) + byte);
        }
    }
    f32x4 acc[3][2];
    #pragma unroll
    for (int i = 0; i < 3; ++i) {
        f32x4 bv;
        #pragma unroll
        for (int r = 0; r < 4; ++r) bv[r] = bi[i][r];
        #pragma unroll
        for (int nt = 0; nt < 2; ++nt) acc[i][nt] = bv;
    }
    #pragma unroll
    for (int i = 0; i < 3; ++i) {
        #pragma unroll
        for (int nt = 0; nt < 2; ++nt) {
            acc[i][nt] = __builtin_amdgcn_mfma_f32_16x16x32_bf16(
                afr[i][0], bfr[nt][0], acc[i][nt], 0, 0, 0);
            acc[i][nt] = __builtin_amdgcn_mfma_f32_16x16x32_bf16(
                afr[i][1], bfr[nt][1], acc[i][nt], 0, 0, 0);
        }
    }
    #pragma unroll
    for (int i = 0; i < 3; ++i) {
        const int mt = 3 * wv + i;
        #pragma unroll
        for (int r = 0; r < 4; ++r) {
            const int row = mt * 16 + (lane >> 4) * 4 + r;
            if (mt < 4) {   // q -> fp32
                float* op = qf + ((size_t)b * 64 + row) * NPIX + pix0 + (lane & 15);
                op[0] = acc[i][0][r]; op[16] = acc[i][1][r];
            } else {        // k,v -> bf16
                ushort* op = kvb + ((size_t)b * 128 + (row - 64)) * NPIX + pix0 + (lane & 15);
                op[0] = f2bf(acc[i][0][r]); op[16] = f2bf(acc[i][1][r]);
            }
        }
    }
}

// ---- attention: K fp32 LDS (from bf16), V bf16 LDS; REP x2 for counter visibility ----
__global__ __launch_bounds__(384) void attn_kernel(
    const float* __restrict__ qf, const ushort* __restrict__ kvb,
    const float* __restrict__ kb, const float* __restrict__ vb,
    const float* __restrict__ rel, float* __restrict__ out)
{
    const int bx   = blockIdx.x;
    const int tile = bx % 3;
    const int c    = (bx / 3) % C_;
    const int b    = bx / (3 * C_);
    const int ho0  = tile * 32;
    const int t    = threadIdx.x;

    __shared__ float  ksl[38 * LDK];
    __shared__ ushort vsl[38 * LDV];

    const float  kbias  = kb[c];
    const ushort vbias_u = f2bf(vb[c]);
    const ushort* kg = kvb + ((size_t)b * 128 +      c) * NPIX;
    const ushort* vg = kvb + ((size_t)b * 128 + 64 + c) * NPIX;

    #pragma unroll
    for (int s0 = 0; s0 < 3; ++s0) {
        const int slot = t + s0 * 384;
        if (slot < 38 * 26) {
            const int rl = slot / 26, c4 = (slot - rl * 26) * 4;
            const int gr = ho0 + rl - 3;
            const bool rin = (gr >= 0 && gr < H_);
            const int grc = rin ? gr : 0;
            float kv[4]; ushort vu[4];
            #pragma unroll
            for (int e = 0; e < 4; ++e) {
                const int gc  = c4 + e - 3;
                const bool inb = rin && (gc >= 0) && (gc < W_);
                const int gcc = gc < 0 ? 0 : (gc > 95 ? 95 : gc);
                const int gi  = grc * W_ + gcc;
                const ushort kl = kg[gi], vl = vg[gi];
                kv[e] = inb ? bf2f(kl) : kbias;
                vu[e] = inb ? vl : vbias_u;
            }
            *reinterpret_cast<float4*>(&ksl[rl * LDK + c4]) =
                make_float4(kv[0], kv[1], kv[2], kv[3]);
            *reinterpret_cast<ushort4*>(&vsl[rl * LDV + c4]) =
                make_ushort4(vu[0], vu[1], vu[2], vu[3]);
        }
    }
    __syncthreads();

    const int r0   = t / 12;
    const int rest = t % 12;
    const int w0   = (rest >> 1) * 16;
    const int half = rest & 1;
    const int ho   = ho0 + r0;

    const float LOG2E = 1.44269504f;
    const float* qp = qf + ((size_t)b * 64 + c) * NPIX + ho * W_ + w0;
    float* op = out + (((size_t)b * C_ + c) * H_ + ho) * W_ + w0 + half * 8;

    // MEASUREMENT: rep x2 (identical work+stores). roff==0 but opaque to the
    // compiler (rule #17), so loads/FMAs can't be CSE'd across reps.
    int roff = 0;
    #pragma unroll 1
    for (int rep = 0; rep < 2; ++rep) {
        asm volatile("" : "+v"(roff));

        float qs[16];
        #pragma unroll
        for (int tt = 0; tt < 16; tt += 4) {
            float4 f = *reinterpret_cast<const float4*>(qp + tt + roff);
            qs[tt] = f.x * LOG2E; qs[tt + 1] = f.y * LOG2E;
            qs[tt + 2] = f.z * LOG2E; qs[tt + 3] = f.w * LOG2E;
        }
        float qsum = 0.f;
        #pragma unroll
        for (int tt = 0; tt < 16; ++tt) qsum += qs[tt];

        float p[49];
        #pragma unroll
        for (int i = 0; i < KS_; ++i) {
            float kr[22];
            const float* kp = &ksl[(r0 + i) * LDK + w0 + roff];
            #pragma unroll
            for (int tt = 0; tt < 20; tt += 4) {
                float4 f = *reinterpret_cast<const float4*>(kp + tt);
                kr[tt] = f.x; kr[tt + 1] = f.y; kr[tt + 2] = f.z; kr[tt + 3] = f.w;
            }
            float2 f2 = *reinterpret_cast<const float2*>(kp + 20);
            kr[20] = f2.x; kr[21] = f2.y;
            #pragma unroll
            for (int j = 0; j < KS_; ++j) {
                float s0 = 0.f, s1 = 0.f, s2 = 0.f, s3 = 0.f;
                #pragma unroll
                for (int tt = 0; tt < 16; tt += 4) {
                    s0 = fmaf(qs[tt],     kr[tt + j],     s0);
                    s1 = fmaf(qs[tt + 1], kr[tt + 1 + j], s1);
                    s2 = fmaf(qs[tt + 2], kr[tt + 2 + j], s2);
                    s3 = fmaf(qs[tt + 3], kr[tt + 3 + j], s3);
                }
                p[i * KS_ + j] = (s0 + s1) + (s2 + s3) + qsum * rel[i * KS_ + j];
            }
        }

        float m0 = p[0], m1 = p[1], m2 = p[2], m3 = p[3];
        #pragma unroll
        for (int kk = 4; kk < 48; kk += 4) {
            m0 = fmaxf(m0, p[kk]);     m1 = fmaxf(m1, p[kk + 1]);
            m2 = fmaxf(m2, p[kk + 2]); m3 = fmaxf(m3, p[kk + 3]);
        }
        float m = fmaxf(fmaxf(fmaxf(m0, m1), fmaxf(m2, m3)), p[48]);

        float e0 = 0.f, e1 = 0.f, e2 = 0.f, e3 = 0.f;
        #pragma unroll
        for (int kk = 0; kk < 48; kk += 4) {
            float a0 = exp2f(p[kk]     - m);
            float a1 = exp2f(p[kk + 1] - m);
            float a2 = exp2f(p[kk + 2] - m);
            float a3 = exp2f(p[kk + 3] - m);
            p[kk] = a0; p[kk + 1] = a1; p[kk + 2] = a2; p[kk + 3] = a3;
            e0 += a0; e1 += a1; e2 += a2; e3 += a3;
        }
        float a48 = exp2f(p[48] - m);
        p[48] = a48;
        const float inv = 1.f / ((e0 + e1) + (e2 + e3) + a48);

        float o8[8];
        #pragma unroll
        for (int d = 0; d < 8; ++d) o8[d] = 0.f;

        #pragma unroll
        for (int i = 0; i < KS_; ++i) {
            const ushort* vp = &vsl[(r0 + i) * LDV + w0 + half * 8 + roff];
            ushort8 u0 = *reinterpret_cast<const ushort8*>(vp);
            ushort8 u1 = *reinterpret_cast<const ushort8*>(vp + 8);
            float vf[14];
            #pragma unroll
            for (int e = 0; e < 8; ++e) vf[e] = bf2f(u0[e]);
            #pragma unroll
            for (int e = 0; e < 6; ++e) vf[8 + e] = bf2f(u1[e]);
            #pragma unroll
            for (int j = 0; j < KS_; ++j) {
                float wgt = p[i * KS_ + j];
                #pragma unroll
                for (int d = 0; d < 8; ++d) o8[d] = fmaf(wgt, vf[d + j], o8[d]);
            }
        }

        #pragma unroll
        for (int d = 0; d < 8; d += 4) {
            float4 f;
            f.x = fmaxf(o8[d]     * inv, 0.f);
            f.y = fmaxf(o8[d + 1] * inv, 0.f);
            f.z = fmaxf(o8[d + 2] * inv, 0.f);
            f.w = fmaxf(o8[d + 3] * inv, 0.f);
            *reinterpret_cast<float4*>(op + d) = f;
        }
    }
}

extern "C" void kernel_launch(void* const* d_in, const int* in_sizes, int n_in,
                              void* d_out, int out_size, void* d_ws, size_t ws_size,
                              hipStream_t stream) {
    const float* in   = (const float*)d_in[0];
    const float* qw   = (const float*)d_in[1];
    const float* qb   = (const float*)d_in[2];
    const float* kw   = (const float*)d_in[3];
    const float* kb   = (const float*)d_in[4];
    const float* vw   = (const float*)d_in[5];
    const float* vb   = (const float*)d_in[6];
    const float* relh = (const float*)d_in[7];
    const float* relw = (const float*)d_in[8];
    float* out = (float*)d_out;

    float*  qf  = (float*)d_ws;                           // [B][64][9216] f32
    ushort* kvb = (ushort*)(qf + (size_t)B_ * 64 * NPIX); // [B][128][9216] bf16
    float*  rel = (float*)(kvb + (size_t)B_ * 128 * NPIX);// [64]

    dim3 cgrid(NPIX / 32, B_);   // 288 x 4 = 1152 blocks
    mfma_conv_kernel<<<cgrid, 256, 0, stream>>>(in, qw, qb, kw, kb, vw, vb,
                                                relh, relw, qf, kvb, rel);

    dim3 agrid(B_ * C_ * 3);     // 768 blocks x 384 threads
    attn_kernel<<<agrid, 384, 0, stream>>>(qf, kvb, kb, vb, rel, out);
}

// Round 12
// 40.146 us; speedup vs baseline: 2.3855x; 1.3519x over previous
//
#include <hip/hip_runtime.h>

#define B_ 4
#define C_ 64
#define H_ 96
#define W_ 96
#define KS_ 7
#define NPIX (H_ * W_)     // 9216
#define PR_ 102            // padded rows
#define PC_ 104            // padded row stride (ushorts), 16B-aligned
#define PSLAB (PR_ * PC_)  // 10608 per (tensor,ch)

typedef __attribute__((ext_vector_type(8))) short short8;
typedef __attribute__((ext_vector_type(8))) unsigned short ushort8;
typedef __attribute__((ext_vector_type(4))) float f32x4;

static __device__ inline ushort f2bf(float f) {
    union { float f; unsigned u; } v; v.f = f;
    unsigned r = (v.u + 0x7fff + ((v.u >> 16) & 1)) >> 16;   // RNE
    return (ushort)r;
}
static __device__ inline float bf2f(ushort u) {
    union { unsigned u; float f; } v; v.u = ((unsigned)u) << 16; return v.f;
}

// ws: qf float[B][64][9216] ; kvb ushort[B][2][64][102][104] (0=k,1=v, padded, border=bias) ; rel float[64]

__global__ __launch_bounds__(256) void mfma_conv_kernel(
    const float* __restrict__ in,
    const float* __restrict__ qw, const float* __restrict__ qb,
    const float* __restrict__ kw, const float* __restrict__ kb,
    const float* __restrict__ vw, const float* __restrict__ vb,
    const float* __restrict__ relh, const float* __restrict__ relw,
    float* __restrict__ qf, ushort* __restrict__ kvb, float* __restrict__ rel_out)
{
    const int b    = blockIdx.y;
    const int pix0 = blockIdx.x * 32;
    const int t    = threadIdx.x;
    const int lane = t & 63;
    const int wv   = t >> 6;

    if (blockIdx.x == 0 && b == 0 && t < 49) {   // rel precompute
        const int i = t / KS_, j = t % KS_;
        float s = 0.f;
        #pragma unroll
        for (int cc = 0; cc < C_ / 2; ++cc)
            s += relh[cc * KS_ + i] + relw[cc * KS_ + j];
        rel_out[t] = s;
    }

    // border fill for this b: 2 tensors x 64 ch x 1200 cells = 153600 cells
    {
        const int base = blockIdx.x * 256 + t;   // 0..73727
        #pragma unroll
        for (int rep = 0; rep < 3; ++rep) {
            const int idx = base + rep * 73728;
            if (idx < 153600) {
                const int cell   = idx % 1200;
                const int chh    = (idx / 1200) & 63;
                const int tensor = idx / 76800;
                int pr, pw;
                if (cell < 312)      { pr = cell / PC_;              pw = cell % PC_; }
                else if (cell < 624) { int j2 = cell - 312; pr = 99 + j2 / PC_; pw = j2 % PC_; }
                else                 { int j2 = cell - 624; pr = 3 + j2 / 6; int s2 = j2 % 6;
                                       pw = (s2 < 3) ? s2 : 96 + s2; }   // 0,1,2 / 99,100,101
                const float bias = (tensor ? vb : kb)[chh];
                kvb[((size_t)(b * 2 + tensor) * C_ + chh) * PSLAB + pr * PC_ + pw] = f2bf(bias);
            }
        }
    }

    __shared__ ushort xs[32 * 64];   // [pix][ch] bf16, byte ^= (pix&7)<<4

    {   // stage X tile (32 pix x 64 ch)
        const int pix = t & 31, cg = t >> 5;
        const float* xp = in + (size_t)b * C_ * NPIX + pix0 + pix;
        #pragma unroll
        for (int g = 0; g < 2; ++g) {
            const int ch = (cg + 8 * g) * 4;
            float x0 = xp[(size_t)(ch    ) * NPIX];
            float x1 = xp[(size_t)(ch + 1) * NPIX];
            float x2 = xp[(size_t)(ch + 2) * NPIX];
            float x3 = xp[(size_t)(ch + 3) * NPIX];
            ushort4 u = make_ushort4(f2bf(x0), f2bf(x1), f2bf(x2), f2bf(x3));
            unsigned byte = (unsigned)(pix * 128 + ch * 2) ^ (unsigned)((pix & 7) << 4);
            *reinterpret_cast<ushort4*>(reinterpret_cast<char*>(xs) + byte) = u;
        }
    }

    // A fragments + bias straight from global
    short8 afr[3][2];
    float  bi[3][4];
    #pragma unroll
    for (int i = 0; i < 3; ++i) {
        const int mt  = 3 * wv + i;
        const int row = mt * 16 + (lane & 15);
        const float* wsrc = (mt < 4) ? qw + row * 64
                          : (mt < 8) ? kw + (row - 64) * 64
                                     : vw + (row - 128) * 64;
        #pragma unroll
        for (int ka = 0; ka < 2; ++ka) {
            const int kk = ka * 32 + (lane >> 4) * 8;
            float4 a = *reinterpret_cast<const float4*>(wsrc + kk);
            float4 c = *reinterpret_cast<const float4*>(wsrc + kk + 4);
            short8 s;
            s[0] = (short)f2bf(a.x); s[1] = (short)f2bf(a.y);
            s[2] = (short)f2bf(a.z); s[3] = (short)f2bf(a.w);
            s[4] = (short)f2bf(c.x); s[5] = (short)f2bf(c.y);
            s[6] = (short)f2bf(c.z); s[7] = (short)f2bf(c.w);
            afr[i][ka] = s;
        }
        const int brow = mt * 16 + (lane >> 4) * 4;
        const float* bsrc = (mt < 4) ? qb + brow
                          : (mt < 8) ? kb + (brow - 64)
                                     : vb + (brow - 128);
        #pragma unroll
        for (int r = 0; r < 4; ++r) bi[i][r] = bsrc[r];
    }
    __syncthreads();

    short8 bfr[2][2];
    #pragma unroll
    for (int nt = 0; nt < 2; ++nt) {
        const int pl = nt * 16 + (lane & 15);
        #pragma unroll
        for (int ka = 0; ka < 2; ++ka) {
            const int kk = ka * 32 + (lane >> 4) * 8;
            unsigned byte = (unsigned)(pl * 128 + kk * 2) ^ (unsigned)((pl & 7) << 4);
            bfr[nt][ka] = *reinterpret_cast<const short8*>(
                reinterpret_cast<const char*>(xs) + byte);
        }
    }
    f32x4 acc[3][2];
    #pragma unroll
    for (int i = 0; i < 3; ++i) {
        f32x4 bv;
        #pragma unroll
        for (int r = 0; r < 4; ++r) bv[r] = bi[i][r];
        #pragma unroll
        for (int nt = 0; nt < 2; ++nt) acc[i][nt] = bv;
    }
    #pragma unroll
    for (int i = 0; i < 3; ++i) {
        #pragma unroll
        for (int nt = 0; nt < 2; ++nt) {
            acc[i][nt] = __builtin_amdgcn_mfma_f32_16x16x32_bf16(
                afr[i][0], bfr[nt][0], acc[i][nt], 0, 0, 0);
            acc[i][nt] = __builtin_amdgcn_mfma_f32_16x16x32_bf16(
                afr[i][1], bfr[nt][1], acc[i][nt], 0, 0, 0);
        }
    }
    #pragma unroll
    for (int i = 0; i < 3; ++i) {
        const int mt = 3 * wv + i;
        #pragma unroll
        for (int nt = 0; nt < 2; ++nt) {
            const int pix = pix0 + nt * 16 + (lane & 15);
            const int h = pix / 96, w = pix - h * 96;
            #pragma unroll
            for (int r = 0; r < 4; ++r) {
                const int row = mt * 16 + (lane >> 4) * 4 + r;
                if (mt < 4) {   // q -> fp32 linear
                    qf[((size_t)b * C_ + row) * NPIX + pix] = acc[i][nt][r];
                } else {        // k,v -> bf16 padded
                    const int tensor = (mt < 8) ? 0 : 1;
                    const int ch = (mt & 3) * 16 + (lane >> 4) * 4 + r;
                    kvb[((size_t)(b * 2 + tensor) * C_ + ch) * PSLAB
                        + (h + 3) * PC_ + (w + 3)] = f2bf(acc[i][nt][r]);
                }
            }
        }
    }
}

// ---- attention: linear aligned slab copy -> LDS (bf16 K and V) ----
__global__ __launch_bounds__(384) void attn_kernel(
    const float* __restrict__ qf, const ushort* __restrict__ kvb,
    const float* __restrict__ rel, float* __restrict__ out)
{
    const int bx   = blockIdx.x;
    const int tile = bx % 3;
    const int c    = (bx / 3) % C_;
    const int b    = bx / (3 * C_);
    const int ho0  = tile * 32;
    const int t    = threadIdx.x;

    __shared__ __align__(16) ushort kvls[2][38 * PC_];   // 2 x 7904 B

    // stage: 2 tensors x 494 ushort8-chunks, pure aligned linear copy
    {
        const ushort* kbase = kvb + ((size_t)(b * 2 + 0) * C_ + c) * PSLAB + ho0 * PC_;
        const ushort* vbase = kvb + ((size_t)(b * 2 + 1) * C_ + c) * PSLAB + ho0 * PC_;
        #pragma unroll
        for (int s0 = 0; s0 < 3; ++s0) {
            const int idx = t + s0 * 384;
            if (idx < 988) {
                const int tensor = idx >= 494;
                const int off = (tensor ? idx - 494 : idx) * 8;
                const ushort* src = (tensor ? vbase : kbase) + off;
                *reinterpret_cast<ushort8*>(&kvls[tensor][off]) =
                    *reinterpret_cast<const ushort8*>(src);
            }
        }
    }
    __syncthreads();

    const int r0   = t / 12;
    const int rest = t % 12;
    const int w0   = (rest >> 1) * 16;
    const int half = rest & 1;
    const int ho   = ho0 + r0;

    const float LOG2E = 1.44269504f;
    const float* qp = qf + ((size_t)b * C_ + c) * NPIX + ho * W_ + w0;
    float qs[16];
    #pragma unroll
    for (int tt = 0; tt < 16; tt += 4) {
        float4 f = *reinterpret_cast<const float4*>(qp + tt);
        qs[tt] = f.x * LOG2E; qs[tt + 1] = f.y * LOG2E;
        qs[tt + 2] = f.z * LOG2E; qs[tt + 3] = f.w * LOG2E;
    }
    float qsum = 0.f;
    #pragma unroll
    for (int tt = 0; tt < 16; ++tt) qsum += qs[tt];

    float p[49];
    #pragma unroll
    for (int i = 0; i < KS_; ++i) {
        const ushort* kp = &kvls[0][(r0 + i) * PC_ + w0];
        ushort8 u0 = *reinterpret_cast<const ushort8*>(kp);
        ushort8 u1 = *reinterpret_cast<const ushort8*>(kp + 8);
        ushort8 u2 = *reinterpret_cast<const ushort8*>(kp + 16);
        float kr[22];
        #pragma unroll
        for (int e = 0; e < 8; ++e) kr[e] = bf2f(u0[e]);
        #pragma unroll
        for (int e = 0; e < 8; ++e) kr[8 + e] = bf2f(u1[e]);
        #pragma unroll
        for (int e = 0; e < 6; ++e) kr[16 + e] = bf2f(u2[e]);
        #pragma unroll
        for (int j = 0; j < KS_; ++j) {
            float s0 = 0.f, s1 = 0.f, s2 = 0.f, s3 = 0.f;
            #pragma unroll
            for (int tt = 0; tt < 16; tt += 4) {
                s0 = fmaf(qs[tt],     kr[tt + j],     s0);
                s1 = fmaf(qs[tt + 1], kr[tt + 1 + j], s1);
                s2 = fmaf(qs[tt + 2], kr[tt + 2 + j], s2);
                s3 = fmaf(qs[tt + 3], kr[tt + 3 + j], s3);
            }
            p[i * KS_ + j] = (s0 + s1) + (s2 + s3) + qsum * rel[i * KS_ + j];
        }
    }

    // softmax (log2 domain, 4-way trees)
    float m0 = p[0], m1 = p[1], m2 = p[2], m3 = p[3];
    #pragma unroll
    for (int kk = 4; kk < 48; kk += 4) {
        m0 = fmaxf(m0, p[kk]);     m1 = fmaxf(m1, p[kk + 1]);
        m2 = fmaxf(m2, p[kk + 2]); m3 = fmaxf(m3, p[kk + 3]);
    }
    float m = fmaxf(fmaxf(fmaxf(m0, m1), fmaxf(m2, m3)), p[48]);

    float e0 = 0.f, e1 = 0.f, e2 = 0.f, e3 = 0.f;
    #pragma unroll
    for (int kk = 0; kk < 48; kk += 4) {
        float a0 = exp2f(p[kk]     - m);
        float a1 = exp2f(p[kk + 1] - m);
        float a2 = exp2f(p[kk + 2] - m);
        float a3 = exp2f(p[kk + 3] - m);
        p[kk] = a0; p[kk + 1] = a1; p[kk + 2] = a2; p[kk + 3] = a3;
        e0 += a0; e1 += a1; e2 += a2; e3 += a3;
    }
    float a48 = exp2f(p[48] - m);
    p[48] = a48;
    const float inv = 1.f / ((e0 + e1) + (e2 + e3) + a48);

    // PV for d = half*8 .. half*8+7
    float o8[8];
    #pragma unroll
    for (int d = 0; d < 8; ++d) o8[d] = 0.f;

    #pragma unroll
    for (int i = 0; i < KS_; ++i) {
        const ushort* vp = &kvls[1][(r0 + i) * PC_ + w0 + half * 8];
        ushort8 u0 = *reinterpret_cast<const ushort8*>(vp);
        ushort8 u1 = *reinterpret_cast<const ushort8*>(vp + 8);
        float vf[14];
        #pragma unroll
        for (int e = 0; e < 8; ++e) vf[e] = bf2f(u0[e]);
        #pragma unroll
        for (int e = 0; e < 6; ++e) vf[8 + e] = bf2f(u1[e]);
        #pragma unroll
        for (int j = 0; j < KS_; ++j) {
            float wgt = p[i * KS_ + j];
            #pragma unroll
            for (int d = 0; d < 8; ++d) o8[d] = fmaf(wgt, vf[d + j], o8[d]);
        }
    }

    float* op = out + (((size_t)b * C_ + c) * H_ + ho) * W_ + w0 + half * 8;
    #pragma unroll
    for (int d = 0; d < 8; d += 4) {
        float4 f;
        f.x = fmaxf(o8[d]     * inv, 0.f);
        f.y = fmaxf(o8[d + 1] * inv, 0.f);
        f.z = fmaxf(o8[d + 2] * inv, 0.f);
        f.w = fmaxf(o8[d + 3] * inv, 0.f);
        *reinterpret_cast<float4*>(op + d) = f;
    }
}

extern "C" void kernel_launch(void* const* d_in, const int* in_sizes, int n_in,
                              void* d_out, int out_size, void* d_ws, size_t ws_size,
                              hipStream_t stream) {
    const float* in   = (const float*)d_in[0];
    const float* qw   = (const float*)d_in[1];
    const float* qb   = (const float*)d_in[2];
    const float* kw   = (const float*)d_in[3];
    const float* kb   = (const float*)d_in[4];
    const float* vw   = (const float*)d_in[5];
    const float* vb   = (const float*)d_in[6];
    const float* relh = (const float*)d_in[7];
    const float* relw = (const float*)d_in[8];
    float* out = (float*)d_out;

    float*  qf  = (float*)d_ws;                            // [B][64][9216] f32
    ushort* kvb = (ushort*)(qf + (size_t)B_ * C_ * NPIX);  // [B][2][64][102][104] bf16
    float*  rel = (float*)(kvb + (size_t)B_ * 2 * C_ * PSLAB);

    dim3 cgrid(NPIX / 32, B_);   // 288 x 4 = 1152 blocks
    mfma_conv_kernel<<<cgrid, 256, 0, stream>>>(in, qw, qb, kw, kb, vw, vb,
                                                relh, relw, qf, kvb, rel);

    dim3 agrid(B_ * C_ * 3);     // 768 blocks x 384 threads
    attn_kernel<<<agrid, 384, 0, stream>>>(qf, kvb, rel, out);
}